// Round 5
// baseline (252.369 us; speedup 1.0000x reference)
//
#include <hip/hip_runtime.h>
#include <hip/hip_bf16.h>

typedef __bf16 bf16x8 __attribute__((ext_vector_type(8)));
typedef unsigned short u16x8 __attribute__((ext_vector_type(8)));
typedef float f32x4 __attribute__((ext_vector_type(4)));
typedef unsigned int u32x4 __attribute__((ext_vector_type(4)));

using gptr_t = const __attribute__((address_space(1))) unsigned int*;
using lptr_t = __attribute__((address_space(3))) unsigned int*;

// ---------------------------------------------------------------------------
// Prep: pack W1 [1280x32] and W2 [32x128] (f32, row-major) into bf16 MFMA
// B-fragment order for mfma_f32_16x16x32_bf16.
// Fragment element (lane l, elem j) <- W[k = kt*32 + (l>>4)*8 + j][n = nt*16 + (l&15)]
// wsB1[((kt*2+nt)*64 + l)*8 + j], wsB2[((nt)*64 + l)*8 + j]
// ---------------------------------------------------------------------------
__global__ __launch_bounds__(256) void prep_w_kernel(
    const float* __restrict__ W1, const float* __restrict__ W2,
    unsigned short* __restrict__ wsB1, unsigned short* __restrict__ wsB2) {
  int tid = blockIdx.x * 256 + threadIdx.x;
  if (tid < 40960) {                      // W1 frags: 40 ktiles * 2 ntiles * 512
    int j = tid & 7, l = (tid >> 3) & 63, nt = (tid >> 9) & 1, kt = tid >> 10;
    int k = kt * 32 + ((l >> 4) << 3) + j;
    int n = nt * 16 + (l & 15);
    __bf16 v = (__bf16)W1[k * 32 + n];
    wsB1[tid] = __builtin_bit_cast(unsigned short, v);
  } else if (tid < 45056) {               // W2 frags: 8 ntiles * 512
    int t = tid - 40960;
    int j = t & 7, l = (t >> 3) & 63, nt = t >> 9;
    int k = ((l >> 4) << 3) + j;
    int n = nt * 16 + (l & 15);
    __bf16 v = (__bf16)W2[k * 128 + n];
    wsB2[t] = __builtin_bit_cast(unsigned short, v);
  }
}

__device__ __forceinline__ u32x4 make_srd(const void* p, unsigned bytes) {
  u32x4 r;
  r[0] = (unsigned)(unsigned long long)p;
  r[1] = (unsigned)(((unsigned long long)p) >> 32);
  r[2] = bytes;
  r[3] = 0x00020000u;
  return r;
}

// --- pipeline primitives ----------------------------------------------------
// XLDS: stage one x tile (64 lanes x 32B = 2KB) into ring slot SLOT via two
// global_load_lds_dwordx4 (in-flight data lives in LDS, zero VGPR cost).
// HW writes lane i's 16B to ldsbase + i*16; we read back at the same mapping.
#define XLDS(SLOT, GP, FOFF)                                                   \
  do {                                                                         \
    __builtin_amdgcn_global_load_lds((gptr_t)(const void*)((GP) + (FOFF)),     \
                                     (lptr_t)(void*)(ringw + (SLOT) * 512),    \
                                     16, 0, 0);                                \
    __builtin_amdgcn_global_load_lds((gptr_t)(const void*)((GP) + (FOFF) + 4), \
                                     (lptr_t)(void*)(ringw + (SLOT) * 512 + 256), \
                                     16, 0, 0);                                \
  } while (0)
// WLD: one weight tile (2 frags x 16B/lane) into pw[SLOT]; tile byte offset
// via soffset SGPR; frag1 at +1024B.
#define WLD(SLOT, SOFF)                                                    \
  asm volatile("buffer_load_dwordx4 %0, %2, %3, %4 offen offset:0"         \
               "\n\tbuffer_load_dwordx4 %1, %2, %3, %4 offen offset:1024"  \
               : "=&v"(pw[SLOT][0]), "=&v"(pw[SLOT][1])                    \
               : "v"(voffw), "s"(srdw), "s"((unsigned)(SOFF))              \
               : "memory")
// VMW: counted wait + scheduling fence.
#define VMW(N)                                                \
  do {                                                        \
    asm volatile("s_waitcnt vmcnt(" #N ")" ::: "memory");     \
    __builtin_amdgcn_sched_barrier(0);                        \
  } while (0)
// CONS: ds_read x slot (lgkmcnt(0) + sched fence, rule #18), convert, 2 MFMAs.
#define CONS(SX, SW)                                                          \
  do {                                                                        \
    f32x4 lo, hi;                                                             \
    asm volatile("ds_read_b128 %0, %2\n\t"                                    \
                 "ds_read_b128 %1, %2 offset:1024\n\t"                        \
                 "s_waitcnt lgkmcnt(0)"                                       \
                 : "=&v"(lo), "=&v"(hi)                                       \
                 : "v"(ldsrd + (SX) * 2048u)                                  \
                 : "memory");                                                 \
    __builtin_amdgcn_sched_barrier(0);                                        \
    bf16x8 a;                                                                 \
    a[0] = (__bf16)lo[0]; a[1] = (__bf16)lo[1];                               \
    a[2] = (__bf16)lo[2]; a[3] = (__bf16)lo[3];                               \
    a[4] = (__bf16)hi[0]; a[5] = (__bf16)hi[1];                               \
    a[6] = (__bf16)hi[2]; a[7] = (__bf16)hi[3];                               \
    acc0 = __builtin_amdgcn_mfma_f32_16x16x32_bf16(                           \
        a, __builtin_bit_cast(bf16x8, pw[SW][0]), acc0, 0, 0, 0);             \
    acc1 = __builtin_amdgcn_mfma_f32_16x16x32_bf16(                           \
        a, __builtin_bit_cast(bf16x8, pw[SW][1]), acc1, 0, 0, 0);             \
  } while (0)

// ---------------------------------------------------------------------------
// One wave per strip of 16 edges. GEMM1: 40 k-tiles; x staged through a
// 6-slot/wave LDS ring (global_load_lds), w through a 4-slot register
// pipeline, one shared counted-vmcnt queue (4 ops/tile). After the loop the
// drained ring is reused as the h-transpose buffer. GEMM2: h @ W2 + b2.
// ---------------------------------------------------------------------------
template <bool USE_WS>
__global__ __launch_bounds__(256, 3) void edge_mlp_kernel(
    const float* __restrict__ src, const float* __restrict__ dst,
    const float* __restrict__ ea, const float* __restrict__ W1,
    const float* __restrict__ b1, const float* __restrict__ W2,
    const float* __restrict__ b2, const unsigned short* __restrict__ wsB1,
    const unsigned short* __restrict__ wsB2, float* __restrict__ out, int nE) {
  __shared__ alignas(16) float ring_s[4][6][512];  // 48 KB: x ring, 12KB/wave
  const int lane = threadIdx.x & 63;
  const int wave = threadIdx.x >> 6;
  const int l15 = lane & 15;
  const int lh = lane >> 4;
  const long strip = (long)blockIdx.x * 4 + wave;
  const long e0 = strip * 16;
  if (e0 >= nE) return;
  long row = e0 + l15;
  if (row >= nE) row = nE - 1;

  float* ringw = &ring_s[wave][0][0];
  const float bias0 = b1[l15];
  const float bias1 = b1[16 + l15];

  f32x4 acc0 = {0.f, 0.f, 0.f, 0.f};
  f32x4 acc1 = {0.f, 0.f, 0.f, 0.f};

  if constexpr (USE_WS) {
    const u32x4 srdw = make_srd(wsB1, 81920u);
    const unsigned voffw = (unsigned)lane * 16u;
    const float* psrc = src + row * 512 + lh * 8;
    const float* pdst = dst + row * 512 + lh * 8;
    const float* pea = ea + row * 256 + lh * 8;
    const unsigned ldsrd =
        (unsigned)(unsigned long long)(__attribute__((address_space(3))) void*)
            ringw + (unsigned)lane * 16u;

    u16x8 pw[4][2];

    // Prologue: X0,W0,X1,W1,X2,W2,X3,W3,X4,X5 (20 vmcnt ops)
    XLDS(0, psrc, 0);    WLD(0, 0);
    XLDS(1, psrc, 32);   WLD(1, 2048);
    XLDS(2, psrc, 64);   WLD(2, 4096);
    XLDS(3, psrc, 96);   WLD(3, 6144);
    XLDS(4, psrc, 128);
    XLDS(5, psrc, 160);

    // Steady: VMW(W); CONS(t%6, t%4); XLDS(t+6); WLD(t+4)
    VMW(16); CONS(0, 0); XLDS(0, psrc, 192); WLD(0, 8192);
    VMW(16); CONS(1, 1); XLDS(1, psrc, 224); WLD(1, 10240);
    VMW(16); CONS(2, 2); XLDS(2, psrc, 256); WLD(2, 12288);
    VMW(16); CONS(3, 3); XLDS(3, psrc, 288); WLD(3, 14336);
    VMW(12); CONS(4, 0); XLDS(4, psrc, 320); WLD(0, 16384);
    VMW(12); CONS(5, 1); XLDS(5, psrc, 352); WLD(1, 18432);
    VMW(12); CONS(0, 2); XLDS(0, psrc, 384); WLD(2, 20480);
    VMW(12); CONS(1, 3); XLDS(1, psrc, 416); WLD(3, 22528);
    VMW(12); CONS(2, 0); XLDS(2, psrc, 448); WLD(0, 24576);
    VMW(12); CONS(3, 1); XLDS(3, psrc, 480); WLD(1, 26624);
    // x-stream: dst (tiles 16..31)
    VMW(12); CONS(4, 2); XLDS(4, pdst, 0);   WLD(2, 28672);
    VMW(12); CONS(5, 3); XLDS(5, pdst, 32);  WLD(3, 30720);
    VMW(12); CONS(0, 0); XLDS(0, pdst, 64);  WLD(0, 32768);
    VMW(12); CONS(1, 1); XLDS(1, pdst, 96);  WLD(1, 34816);
    VMW(12); CONS(2, 2); XLDS(2, pdst, 128); WLD(2, 36864);
    VMW(12); CONS(3, 3); XLDS(3, pdst, 160); WLD(3, 38912);
    VMW(12); CONS(4, 0); XLDS(4, pdst, 192); WLD(0, 40960);
    VMW(12); CONS(5, 1); XLDS(5, pdst, 224); WLD(1, 43008);
    VMW(12); CONS(0, 2); XLDS(0, pdst, 256); WLD(2, 45056);
    VMW(12); CONS(1, 3); XLDS(1, pdst, 288); WLD(3, 47104);
    VMW(12); CONS(2, 0); XLDS(2, pdst, 320); WLD(0, 49152);
    VMW(12); CONS(3, 1); XLDS(3, pdst, 352); WLD(1, 51200);
    VMW(12); CONS(4, 2); XLDS(4, pdst, 384); WLD(2, 53248);
    VMW(12); CONS(5, 3); XLDS(5, pdst, 416); WLD(3, 55296);
    VMW(12); CONS(0, 0); XLDS(0, pdst, 448); WLD(0, 57344);
    VMW(12); CONS(1, 1); XLDS(1, pdst, 480); WLD(1, 59392);
    // x-stream: edge_attr (tiles 32..39)
    VMW(12); CONS(2, 2); XLDS(2, pea, 0);    WLD(2, 61440);
    VMW(12); CONS(3, 3); XLDS(3, pea, 32);   WLD(3, 63488);
    VMW(12); CONS(4, 0); XLDS(4, pea, 64);   WLD(0, 65536);
    VMW(12); CONS(5, 1); XLDS(5, pea, 96);   WLD(1, 67584);
    VMW(12); CONS(0, 2); XLDS(0, pea, 128);  WLD(2, 69632);
    VMW(12); CONS(1, 3); XLDS(1, pea, 160);  WLD(3, 71680);
    VMW(12); CONS(2, 0); XLDS(2, pea, 192);  WLD(0, 73728);
    VMW(12); CONS(3, 1); XLDS(3, pea, 224);  WLD(1, 75776);
    // tail
    VMW(12); CONS(4, 2);                     WLD(2, 77824);
    VMW(10); CONS(5, 3);                     WLD(3, 79872);
    VMW(8);  CONS(0, 0);
    VMW(4);  CONS(1, 1);
    VMW(2);  CONS(2, 2);
    VMW(0);  CONS(3, 3);
  } else {
    // correctness fallback (no workspace): plain serial loop
    for (int t = 0; t < 40; ++t) {
      const float* p = (t < 16) ? (src + row * 512 + t * 32 + lh * 8)
                     : (t < 32) ? (dst + row * 512 + (t - 16) * 32 + lh * 8)
                                : (ea + row * 256 + (t - 32) * 32 + lh * 8);
      f32x4 lo = *(const f32x4*)p;
      f32x4 hi = *(const f32x4*)(p + 4);
      bf16x8 a, bf0, bf1;
      a[0] = (__bf16)lo[0]; a[1] = (__bf16)lo[1];
      a[2] = (__bf16)lo[2]; a[3] = (__bf16)lo[3];
      a[4] = (__bf16)hi[0]; a[5] = (__bf16)hi[1];
      a[6] = (__bf16)hi[2]; a[7] = (__bf16)hi[3];
#pragma unroll
      for (int j = 0; j < 8; ++j) {
        int k = t * 32 + lh * 8 + j;
        bf0[j] = (__bf16)W1[k * 32 + l15];
        bf1[j] = (__bf16)W1[k * 32 + 16 + l15];
      }
      acc0 = __builtin_amdgcn_mfma_f32_16x16x32_bf16(a, bf0, acc0, 0, 0, 0);
      acc1 = __builtin_amdgcn_mfma_f32_16x16x32_bf16(a, bf1, acc1, 0, 0, 0);
    }
  }

  // ---- bias + ELU, write h (bf16) into the (drained) ring as transpose buf
  unsigned short* hl = (unsigned short*)ringw;  // 16 rows x stride 40
#pragma unroll
  for (int r = 0; r < 4; ++r) {
    int hrow = lh * 4 + r;  // C/D layout: row=(lane>>4)*4+reg, col=lane&15
    float h0 = acc0[r] + bias0;
    float h1 = acc1[r] + bias1;
    h0 = h0 > 0.f ? h0 : (__expf(h0) - 1.f);
    h1 = h1 > 0.f ? h1 : (__expf(h1) - 1.f);
    __bf16 v0 = (__bf16)h0, v1 = (__bf16)h1;
    hl[hrow * 40 + l15] = __builtin_bit_cast(unsigned short, v0);
    hl[hrow * 40 + 16 + l15] = __builtin_bit_cast(unsigned short, v1);
  }
  // wave-local transpose: drain ds_writes, fence, read A-fragment layout
  asm volatile("s_waitcnt lgkmcnt(0)" ::: "memory");
  __builtin_amdgcn_sched_barrier(0);
  bf16x8 ha =
      __builtin_bit_cast(bf16x8, *(const u16x8*)(hl + l15 * 40 + lh * 8));

  // ---- GEMM2: out tiles over 8 ntiles of 16 cols ----
  f32x4 o[8];
#pragma unroll
  for (int nt = 0; nt < 8; ++nt) {
    bf16x8 bw;
    if (USE_WS) {
      bw = __builtin_bit_cast(bf16x8, *(const u16x8*)(wsB2 + nt * 512 + lane * 8));
    } else {
#pragma unroll
      for (int j = 0; j < 8; ++j)
        bw[j] = (__bf16)W2[(lh * 8 + j) * 128 + nt * 16 + l15];
    }
    f32x4 z = {0.f, 0.f, 0.f, 0.f};
    o[nt] = __builtin_amdgcn_mfma_f32_16x16x32_bf16(ha, bw, z, 0, 0, 0);
  }

#pragma unroll
  for (int nt = 0; nt < 8; ++nt) {
    float bb = b2[nt * 16 + l15];
#pragma unroll
    for (int r = 0; r < 4; ++r) {
      long e = e0 + lh * 4 + r;
      if (e < nE) out[e * 128 + nt * 16 + l15] = o[nt][r] + bb;
    }
  }
}

extern "C" void kernel_launch(void* const* d_in, const int* in_sizes, int n_in,
                              void* d_out, int out_size, void* d_ws,
                              size_t ws_size, hipStream_t stream) {
  const float* src = (const float*)d_in[0];
  const float* dst = (const float*)d_in[1];
  const float* ea = (const float*)d_in[2];
  // d_in[3] = u (unused), d_in[4] = batch (unused)
  const float* W1 = (const float*)d_in[5];
  const float* b1 = (const float*)d_in[6];
  const float* W2 = (const float*)d_in[7];
  const float* b2 = (const float*)d_in[8];
  float* out = (float*)d_out;

  const int nE = in_sizes[0] / 512;             // 200000
  const long strips = (nE + 15) / 16;           // 12500
  const int nblocks = (int)((strips + 3) / 4);  // 3125

  unsigned short* wsB1 = (unsigned short*)d_ws;
  unsigned short* wsB2 = wsB1 + 40960;
  const bool use_ws = ws_size >= 45056 * sizeof(unsigned short);

  if (use_ws) {
    prep_w_kernel<<<176, 256, 0, stream>>>(W1, W2, wsB1, wsB2);
    edge_mlp_kernel<true><<<nblocks, 256, 0, stream>>>(
        src, dst, ea, W1, b1, W2, b2, wsB1, wsB2, out, nE);
  } else {
    edge_mlp_kernel<false><<<nblocks, 256, 0, stream>>>(
        src, dst, ea, W1, b1, W2, b2, nullptr, nullptr, out, nE);
  }
}

// Round 6
// 246.822 us; speedup vs baseline: 1.0225x; 1.0225x over previous
//
#include <hip/hip_runtime.h>
#include <hip/hip_bf16.h>

typedef __bf16 bf16x8 __attribute__((ext_vector_type(8)));
typedef unsigned short u16x8 __attribute__((ext_vector_type(8)));
typedef float f32x4 __attribute__((ext_vector_type(4)));
typedef unsigned int u32x4 __attribute__((ext_vector_type(4)));

using gptr_t = const __attribute__((address_space(1))) unsigned int*;
using lptr_t = __attribute__((address_space(3))) unsigned int*;
#define gp(x) ((gptr_t)(const void*)(x))
#define lp(x) ((lptr_t)(void*)(x))

// ---------------------------------------------------------------------------
// Prep: pack W1 [1280x32] and W2 [32x128] (f32, row-major) into bf16 MFMA
// B-fragment order for mfma_f32_16x16x32_bf16.
// (lane l, elem j) <- W[k = kt*32 + (l>>4)*8 + j][n = nt*16 + (l&15)]
// wsB1[((kt*2+nt)*64 + l)*8 + j], wsB2[((nt)*64 + l)*8 + j]
// ---------------------------------------------------------------------------
__global__ __launch_bounds__(256) void prep_w_kernel(
    const float* __restrict__ W1, const float* __restrict__ W2,
    unsigned short* __restrict__ wsB1, unsigned short* __restrict__ wsB2) {
  int tid = blockIdx.x * 256 + threadIdx.x;
  if (tid < 40960) {                      // W1 frags: 40 ktiles * 2 ntiles * 512
    int j = tid & 7, l = (tid >> 3) & 63, nt = (tid >> 9) & 1, kt = tid >> 10;
    int k = kt * 32 + ((l >> 4) << 3) + j;
    int n = nt * 16 + (l & 15);
    __bf16 v = (__bf16)W1[k * 32 + n];
    wsB1[tid] = __builtin_bit_cast(unsigned short, v);
  } else if (tid < 45056) {               // W2 frags: 8 ntiles * 512
    int t = tid - 40960;
    int j = t & 7, l = (t >> 3) & 63, nt = t >> 9;
    int k = ((l >> 4) << 3) + j;
    int n = nt * 16 + (l & 15);
    __bf16 v = (__bf16)W2[k * 128 + n];
    wsB2[t] = __builtin_bit_cast(unsigned short, v);
  }
}

__device__ __forceinline__ u32x4 make_srd(const void* p, unsigned bytes) {
  u32x4 r;
  r[0] = (unsigned)(unsigned long long)p;
  r[1] = (unsigned)(((unsigned long long)p) >> 32);
  r[2] = bytes;
  r[3] = 0x00020000u;
  return r;
}

// --- pipeline primitives ----------------------------------------------------
// XST: stage one 16-row x 64-col f32 supertile (4KB) into ring slot SLOT.
// 4 x global_load_lds, each = 4 rows x 256B CONTIGUOUS runs (coalesced).
// Source is pre-swizzled per lane (xoffF includes ^ (row&3)<<5); LDS dest is
// linear (rule 21: inverse-swz SOURCE + swz on READ, LDS stays linear).
#define XST(SLOT, P, FOFF, RSTR)                                               \
  do {                                                                         \
    __builtin_amdgcn_global_load_lds(gp((P) + (FOFF)),                         \
                                     lp(ringw + (SLOT) * 1024), 16, 0, 0);     \
    __builtin_amdgcn_global_load_lds(gp((P) + (FOFF) + 4 * (RSTR)),            \
                                     lp(ringw + (SLOT) * 1024 + 256), 16, 0, 0); \
    __builtin_amdgcn_global_load_lds(gp((P) + (FOFF) + 8 * (RSTR)),            \
                                     lp(ringw + (SLOT) * 1024 + 512), 16, 0, 0); \
    __builtin_amdgcn_global_load_lds(gp((P) + (FOFF) + 12 * (RSTR)),           \
                                     lp(ringw + (SLOT) * 1024 + 768), 16, 0, 0); \
  } while (0)
// WLD: one weight k-tile (2 frags x 16B/lane, coalesced) into pw[SLOT].
#define WLD(SLOT, SOFF)                                                    \
  asm volatile("buffer_load_dwordx4 %0, %2, %3, %4 offen offset:0"         \
               "\n\tbuffer_load_dwordx4 %1, %2, %3, %4 offen offset:1024"  \
               : "=&v"(pw[SLOT][0]), "=&v"(pw[SLOT][1])                    \
               : "v"(voffw), "s"(srdw), "s"((unsigned)(SOFF))              \
               : "memory")
// VMW: counted wait + scheduling fence (rule #18).
#define VMW(N)                                                \
  do {                                                        \
    asm volatile("s_waitcnt vmcnt(" #N ")" ::: "memory");     \
    __builtin_amdgcn_sched_barrier(0);                        \
  } while (0)
// CONS(T): consume k-tile T: swizzled ds_read of the lane's 32B A-chunk,
// cvt to bf16, 2 MFMAs against pw[T%6]. LDS slot (T>>1)%3, half-tile T&1.
#define CONS(T)                                                               \
  do {                                                                        \
    f32x4 lo, hi;                                                             \
    asm volatile("ds_read_b128 %0, %2\n\t"                                    \
                 "ds_read_b128 %1, %2 offset:16\n\t"                          \
                 "s_waitcnt lgkmcnt(0)"                                       \
                 : "=&v"(lo), "=&v"(hi)                                       \
                 : "v"(ldsrd + (unsigned)((((T) >> 1) % 3) * 4096 +           \
                                          ((T)&1) * 128))                     \
                 : "memory");                                                 \
    __builtin_amdgcn_sched_barrier(0);                                        \
    bf16x8 a;                                                                 \
    a[0] = (__bf16)lo[0]; a[1] = (__bf16)lo[1];                               \
    a[2] = (__bf16)lo[2]; a[3] = (__bf16)lo[3];                               \
    a[4] = (__bf16)hi[0]; a[5] = (__bf16)hi[1];                               \
    a[6] = (__bf16)hi[2]; a[7] = (__bf16)hi[3];                               \
    acc0 = __builtin_amdgcn_mfma_f32_16x16x32_bf16(                           \
        a, __builtin_bit_cast(bf16x8, pw[(T) % 6][0]), acc0, 0, 0, 0);        \
    acc1 = __builtin_amdgcn_mfma_f32_16x16x32_bf16(                           \
        a, __builtin_bit_cast(bf16x8, pw[(T) % 6][1]), acc1, 0, 0, 0);        \
  } while (0)

// ---------------------------------------------------------------------------
// One wave per strip of 16 edges. GEMM1: 20 coalesced 64-col supertiles
// (= 40 k-tiles) through a 3-slot/wave LDS ring; W through a 6-slot register
// pipeline; one counted-vmcnt queue (6 ops/supertile, steady wait = 6).
// XOR swizzle (row&3)<<5 on source+read keeps banks spread and A-frags
// contiguous. Then per-wave LDS h-transpose, GEMM2: out = h @ W2 + b2.
// ---------------------------------------------------------------------------
template <bool USE_WS>
__global__ __launch_bounds__(256, 3) void edge_mlp_kernel(
    const float* __restrict__ src, const float* __restrict__ dst,
    const float* __restrict__ ea, const float* __restrict__ W1,
    const float* __restrict__ b1, const float* __restrict__ W2,
    const float* __restrict__ b2, const unsigned short* __restrict__ wsB1,
    const unsigned short* __restrict__ wsB2, float* __restrict__ out, int nE) {
  __shared__ alignas(16) float ring_s[4][3][1024];  // 48 KB: 3x4KB per wave
  const int lane = threadIdx.x & 63;
  const int wave = threadIdx.x >> 6;
  const int l15 = lane & 15;
  const int lh = lane >> 4;
  const long strip = (long)blockIdx.x * 4 + wave;
  const long e0 = strip * 16;
  if (e0 >= nE) return;

  float* ringw = &ring_s[wave][0][0];
  const float bias0 = b1[l15];
  const float bias1 = b1[16 + l15];

  f32x4 acc0 = {0.f, 0.f, 0.f, 0.f};
  f32x4 acc1 = {0.f, 0.f, 0.f, 0.f};

  if constexpr (USE_WS) {
    const u32x4 srdw = make_srd(wsB1, 81920u);
    const unsigned voffw = (unsigned)lane * 16u;
    // staging lane map: row = i*4 + lh, chunk = l15 (256B contiguous rows)
    // pre-swizzled source col offset (floats): (l15*4) ^ (lh*8)
    const unsigned xoffF = ((unsigned)l15 * 4u) ^ ((unsigned)lh * 8u);
    const float* pSL = src + (size_t)(e0 + lh) * 512 + xoffF;
    const float* pDL = dst + (size_t)(e0 + lh) * 512 + xoffF;
    const float* pEL = ea + (size_t)(e0 + lh) * 256 + xoffF;
    // ds_read lane map: row = l15, k-chunk = lh*32B, swz key = l15&3
    const unsigned rdswz = (unsigned)l15 * 256u +
                           (((unsigned)lh * 32u) ^ ((unsigned)(l15 & 3) << 5));
    const unsigned ldsrd =
        (unsigned)(unsigned long long)(__attribute__((address_space(3))) void*)
            ringw + rdswz;

    u16x8 pw[6][2];

    // Prologue: groups 0,1 (12 vmem ops)
    XST(0, pSL, 0, 512);  WLD(0, 0);    WLD(1, 2048);
    XST(1, pSL, 64, 512); WLD(2, 4096); WLD(3, 6144);
    // Steady: VMW(6); consume supertile s; stage supertile s+2
    VMW(6); CONS(0);  CONS(1);  XST(2, pSL, 128, 512); WLD(4, 8192);  WLD(5, 10240);
    VMW(6); CONS(2);  CONS(3);  XST(0, pSL, 192, 512); WLD(0, 12288); WLD(1, 14336);
    VMW(6); CONS(4);  CONS(5);  XST(1, pSL, 256, 512); WLD(2, 16384); WLD(3, 18432);
    VMW(6); CONS(6);  CONS(7);  XST(2, pSL, 320, 512); WLD(4, 20480); WLD(5, 22528);
    VMW(6); CONS(8);  CONS(9);  XST(0, pSL, 384, 512); WLD(0, 24576); WLD(1, 26624);
    VMW(6); CONS(10); CONS(11); XST(1, pSL, 448, 512); WLD(2, 28672); WLD(3, 30720);
    VMW(6); CONS(12); CONS(13); XST(2, pDL, 0, 512);   WLD(4, 32768); WLD(5, 34816);
    VMW(6); CONS(14); CONS(15); XST(0, pDL, 64, 512);  WLD(0, 36864); WLD(1, 38912);
    VMW(6); CONS(16); CONS(17); XST(1, pDL, 128, 512); WLD(2, 40960); WLD(3, 43008);
    VMW(6); CONS(18); CONS(19); XST(2, pDL, 192, 512); WLD(4, 45056); WLD(5, 47104);
    VMW(6); CONS(20); CONS(21); XST(0, pDL, 256, 512); WLD(0, 49152); WLD(1, 51200);
    VMW(6); CONS(22); CONS(23); XST(1, pDL, 320, 512); WLD(2, 53248); WLD(3, 55296);
    VMW(6); CONS(24); CONS(25); XST(2, pDL, 384, 512); WLD(4, 57344); WLD(5, 59392);
    VMW(6); CONS(26); CONS(27); XST(0, pDL, 448, 512); WLD(0, 61440); WLD(1, 63488);
    VMW(6); CONS(28); CONS(29); XST(1, pEL, 0, 256);   WLD(2, 65536); WLD(3, 67584);
    VMW(6); CONS(30); CONS(31); XST(2, pEL, 64, 256);  WLD(4, 69632); WLD(5, 71680);
    VMW(6); CONS(32); CONS(33); XST(0, pEL, 128, 256); WLD(0, 73728); WLD(1, 75776);
    VMW(6); CONS(34); CONS(35); XST(1, pEL, 192, 256); WLD(2, 77824); WLD(3, 79872);
    // Tail
    VMW(6); CONS(36); CONS(37);
    VMW(0); CONS(38); CONS(39);
  } else {
    // correctness fallback (no workspace / nE not multiple of 16)
    long rowf = e0 + l15;
    if (rowf >= nE) rowf = nE - 1;
    for (int t = 0; t < 40; ++t) {
      const float* p = (t < 16) ? (src + rowf * 512 + t * 32 + lh * 8)
                     : (t < 32) ? (dst + rowf * 512 + (t - 16) * 32 + lh * 8)
                                : (ea + rowf * 256 + (t - 32) * 32 + lh * 8);
      f32x4 lo = *(const f32x4*)p;
      f32x4 hi = *(const f32x4*)(p + 4);
      bf16x8 a, bf0, bf1;
      a[0] = (__bf16)lo[0]; a[1] = (__bf16)lo[1];
      a[2] = (__bf16)lo[2]; a[3] = (__bf16)lo[3];
      a[4] = (__bf16)hi[0]; a[5] = (__bf16)hi[1];
      a[6] = (__bf16)hi[2]; a[7] = (__bf16)hi[3];
#pragma unroll
      for (int j = 0; j < 8; ++j) {
        int k = t * 32 + lh * 8 + j;
        bf0[j] = (__bf16)W1[k * 32 + l15];
        bf1[j] = (__bf16)W1[k * 32 + 16 + l15];
      }
      acc0 = __builtin_amdgcn_mfma_f32_16x16x32_bf16(a, bf0, acc0, 0, 0, 0);
      acc1 = __builtin_amdgcn_mfma_f32_16x16x32_bf16(a, bf1, acc1, 0, 0, 0);
    }
  }

  // ---- bias + ELU, write h (bf16) into the (drained) ring as transpose buf
  unsigned short* hl = (unsigned short*)ringw;  // 16 rows x stride 40
#pragma unroll
  for (int r = 0; r < 4; ++r) {
    int hrow = lh * 4 + r;  // C/D layout: row=(lane>>4)*4+reg, col=lane&15
    float h0 = acc0[r] + bias0;
    float h1 = acc1[r] + bias1;
    h0 = h0 > 0.f ? h0 : (__expf(h0) - 1.f);
    h1 = h1 > 0.f ? h1 : (__expf(h1) - 1.f);
    __bf16 v0 = (__bf16)h0, v1 = (__bf16)h1;
    hl[hrow * 40 + l15] = __builtin_bit_cast(unsigned short, v0);
    hl[hrow * 40 + 16 + l15] = __builtin_bit_cast(unsigned short, v1);
  }
  // wave-local transpose: drain ds_writes, fence, read A-fragment layout
  asm volatile("s_waitcnt lgkmcnt(0)" ::: "memory");
  __builtin_amdgcn_sched_barrier(0);
  bf16x8 ha =
      __builtin_bit_cast(bf16x8, *(const u16x8*)(hl + l15 * 40 + lh * 8));

  // ---- GEMM2: out tiles over 8 ntiles of 16 cols ----
  f32x4 o[8];
#pragma unroll
  for (int nt = 0; nt < 8; ++nt) {
    bf16x8 bw;
    if (USE_WS) {
      bw = __builtin_bit_cast(bf16x8, *(const u16x8*)(wsB2 + nt * 512 + lane * 8));
    } else {
#pragma unroll
      for (int j = 0; j < 8; ++j)
        bw[j] = (__bf16)W2[(lh * 8 + j) * 128 + nt * 16 + l15];
    }
    f32x4 z = {0.f, 0.f, 0.f, 0.f};
    o[nt] = __builtin_amdgcn_mfma_f32_16x16x32_bf16(ha, bw, z, 0, 0, 0);
  }

#pragma unroll
  for (int nt = 0; nt < 8; ++nt) {
    float bb = b2[nt * 16 + l15];
#pragma unroll
    for (int r = 0; r < 4; ++r) {
      long e = e0 + lh * 4 + r;
      if (e < nE) out[e * 128 + nt * 16 + l15] = o[nt][r] + bb;
    }
  }
}

extern "C" void kernel_launch(void* const* d_in, const int* in_sizes, int n_in,
                              void* d_out, int out_size, void* d_ws,
                              size_t ws_size, hipStream_t stream) {
  const float* src = (const float*)d_in[0];
  const float* dst = (const float*)d_in[1];
  const float* ea = (const float*)d_in[2];
  // d_in[3] = u (unused), d_in[4] = batch (unused)
  const float* W1 = (const float*)d_in[5];
  const float* b1 = (const float*)d_in[6];
  const float* W2 = (const float*)d_in[7];
  const float* b2 = (const float*)d_in[8];
  float* out = (float*)d_out;

  const int nE = in_sizes[0] / 512;             // 200000
  const long strips = (nE + 15) / 16;           // 12500
  const int nblocks = (int)((strips + 3) / 4);  // 3125

  unsigned short* wsB1 = (unsigned short*)d_ws;
  unsigned short* wsB2 = wsB1 + 40960;
  const bool use_ws =
      ws_size >= 45056 * sizeof(unsigned short) && (nE & 15) == 0;

  if (use_ws) {
    prep_w_kernel<<<176, 256, 0, stream>>>(W1, W2, wsB1, wsB2);
    edge_mlp_kernel<true><<<nblocks, 256, 0, stream>>>(
        src, dst, ea, W1, b1, W2, b2, wsB1, wsB2, out, nE);
  } else {
    edge_mlp_kernel<false><<<nblocks, 256, 0, stream>>>(
        src, dst, ea, W1, b1, W2, b2, nullptr, nullptr, out, nE);
  }
}

// Round 7
// 244.523 us; speedup vs baseline: 1.0321x; 1.0094x over previous
//
#include <hip/hip_runtime.h>
#include <hip/hip_bf16.h>

typedef __bf16 bf16x8 __attribute__((ext_vector_type(8)));
typedef unsigned short u16x8 __attribute__((ext_vector_type(8)));
typedef float f32x4 __attribute__((ext_vector_type(4)));

using gptr_t = const __attribute__((address_space(1))) unsigned int*;
using lptr_t = __attribute__((address_space(3))) unsigned int*;
#define gp(x) ((gptr_t)(const void*)(x))
#define lp(x) ((lptr_t)(void*)(x))

// ---------------------------------------------------------------------------
// Prep: pack W1 [1280x32] and W2 [32x128] (f32, row-major) into bf16 MFMA
// B-fragment order for mfma_f32_16x16x32_bf16.
// (lane l, elem j) <- W[k = kt*32 + (l>>4)*8 + j][n = nt*16 + (l&15)]
// wsB1[((kt*2+nt)*64 + l)*8 + j], wsB2[((nt)*64 + l)*8 + j]
// ---------------------------------------------------------------------------
__global__ __launch_bounds__(256) void prep_w_kernel(
    const float* __restrict__ W1, const float* __restrict__ W2,
    unsigned short* __restrict__ wsB1, unsigned short* __restrict__ wsB2) {
  int tid = blockIdx.x * 256 + threadIdx.x;
  if (tid < 40960) {                      // W1 frags: 40 ktiles * 2 ntiles * 512
    int j = tid & 7, l = (tid >> 3) & 63, nt = (tid >> 9) & 1, kt = tid >> 10;
    int k = kt * 32 + ((l >> 4) << 3) + j;
    int n = nt * 16 + (l & 15);
    __bf16 v = (__bf16)W1[k * 32 + n];
    wsB1[tid] = __builtin_bit_cast(unsigned short, v);
  } else if (tid < 45056) {               // W2 frags: 8 ntiles * 512
    int t = tid - 40960;
    int j = t & 7, l = (t >> 3) & 63, nt = t >> 9;
    int k = ((l >> 4) << 3) + j;
    int n = nt * 16 + (l & 15);
    __bf16 v = (__bf16)W2[k * 128 + n];
    wsB2[t] = __builtin_bit_cast(unsigned short, v);
  }
}

// ---------------------------------------------------------------------------
// Block-cooperative m97-style kernel: 256 threads = 64 edges/block.
// x = [src(512) | dst(512) | ea(256)] chunked into 20 x 64-col tiles.
// Double-buffered LDS xb[2][64][64] f32; per iteration: stage(c+1) via
// global_load_lds (16B/thread x 4 rounds, 4x256B runs per instr), consume(c)
// (each wave: 2 k-tiles x 2 MFMAs), one __syncthreads (vmcnt0+barrier; the
// m97/m114 pattern — overlap comes from 4 resident blocks/CU).
// Pair-granule XOR swizzle: stored 32B-pair position pp = gpair ^ (row&7),
// applied on the global SOURCE (LDS stays linear, rule 21) and on the read.
// ---------------------------------------------------------------------------
template <bool USE_WS>
__global__ __launch_bounds__(256) void edge_mlp_kernel(
    const float* __restrict__ src, const float* __restrict__ dst,
    const float* __restrict__ ea, const float* __restrict__ W1,
    const float* __restrict__ b1, const float* __restrict__ W2,
    const float* __restrict__ b2, const unsigned short* __restrict__ wsB1,
    const unsigned short* __restrict__ wsB2, float* __restrict__ out, int nE) {
  __shared__ alignas(16) float xb[2][64][64];  // 32 KB
  const int lane = threadIdx.x & 63;
  const int wave = threadIdx.x >> 6;
  const int l15 = lane & 15;
  const int lh = lane >> 4;

  // m204 bijective XCD swizzle (nwg % 8 != 0 safe)
  const int nwg = gridDim.x;
  const int q = nwg >> 3, rmd = nwg & 7;
  const int xcd = (int)blockIdx.x & 7, idx = (int)blockIdx.x >> 3;
  const int bid =
      (xcd < rmd ? xcd * (q + 1) : rmd * (q + 1) + (xcd - rmd) * q) + idx;

  const long e0 = (long)bid * 64;          // block's first edge
  if (e0 >= nE) return;
  const long erow = e0 + wave * 16 + l15;  // this lane's output edge (GEMM rows)

  const float bias0 = b1[l15];
  const float bias1 = b1[16 + l15];

  f32x4 acc0 = {0.f, 0.f, 0.f, 0.f};
  f32x4 acc1 = {0.f, 0.f, 0.f, 0.f};

  if constexpr (USE_WS) {
    // ---- staging: chunk c -> buffer b ----
    auto stage = [&](int c, int b) {
#pragma unroll
      for (int r = 0; r < 4; ++r) {
        const int row_l = r * 16 + wave * 4 + (lane >> 4);  // 0..63
        const int i = lane & 15;  // stored granule position (16B units)
        // inverse swizzle on source: stored pair (i>>1) holds source pair
        // (i>>1)^(row&7); low bit (16B within pair) passes through.
        const int g = ((((i >> 1) ^ (row_l & 7)) << 1) | (i & 1));
        const float* p;
        if (c < 8)
          p = src + (e0 + row_l) * 512 + c * 64 + g * 4;
        else if (c < 16)
          p = dst + (e0 + row_l) * 512 + (c - 8) * 64 + g * 4;
        else
          p = ea + (e0 + row_l) * 256 + (c - 16) * 64 + g * 4;
        // LDS dest: wave-uniform base; HW adds lane*16B -> rows wave*4..+3
        __builtin_amdgcn_global_load_lds(
            gp(p), lp(&xb[b][r * 16 + wave * 4][0]), 16, 0, 0);
      }
    };

    // ---- consume: chunk c from buffer b (2 k-tiles x 2 MFMAs per wave) ----
    auto consume = [&](int c, int b) {
      const int lr = wave * 16 + l15;  // this lane's LDS row
#pragma unroll
      for (int kk = 0; kk < 2; ++kk) {
        const int pp = (kk * 4 + lh) ^ (lr & 7);  // stored 32B-pair position
        const f32x4* ap =
            (const f32x4*)((const char*)&xb[b][lr][0] + pp * 32);
        f32x4 lo = ap[0], hi = ap[1];
        bf16x8 a;
        a[0] = (__bf16)lo[0]; a[1] = (__bf16)lo[1];
        a[2] = (__bf16)lo[2]; a[3] = (__bf16)lo[3];
        a[4] = (__bf16)hi[0]; a[5] = (__bf16)hi[1];
        a[6] = (__bf16)hi[2]; a[7] = (__bf16)hi[3];
        const int t = c * 2 + kk;  // global k-tile 0..39
        bf16x8 b0 = __builtin_bit_cast(
            bf16x8, *(const u16x8*)(wsB1 + (t * 2 + 0) * 512 + lane * 8));
        bf16x8 b1f = __builtin_bit_cast(
            bf16x8, *(const u16x8*)(wsB1 + (t * 2 + 1) * 512 + lane * 8));
        acc0 = __builtin_amdgcn_mfma_f32_16x16x32_bf16(a, b0, acc0, 0, 0, 0);
        acc1 = __builtin_amdgcn_mfma_f32_16x16x32_bf16(a, b1f, acc1, 0, 0, 0);
      }
    };

    stage(0, 0);
    __syncthreads();
#pragma unroll
    for (int c = 0; c < 20; ++c) {
      if (c < 19) stage(c + 1, (c + 1) & 1);
      consume(c, c & 1);
      if (c < 19) __syncthreads();
    }
  } else {
    // correctness fallback (no workspace / nE not multiple of 64)
    long rowf = erow < nE ? erow : nE - 1;
    for (int t = 0; t < 40; ++t) {
      const float* p = (t < 16) ? (src + rowf * 512 + t * 32 + lh * 8)
                     : (t < 32) ? (dst + rowf * 512 + (t - 16) * 32 + lh * 8)
                                : (ea + rowf * 256 + (t - 32) * 32 + lh * 8);
      f32x4 lo = *(const f32x4*)p;
      f32x4 hi = *(const f32x4*)(p + 4);
      bf16x8 a, bf0, bf1;
      a[0] = (__bf16)lo[0]; a[1] = (__bf16)lo[1];
      a[2] = (__bf16)lo[2]; a[3] = (__bf16)lo[3];
      a[4] = (__bf16)hi[0]; a[5] = (__bf16)hi[1];
      a[6] = (__bf16)hi[2]; a[7] = (__bf16)hi[3];
#pragma unroll
      for (int j = 0; j < 8; ++j) {
        int k = t * 32 + lh * 8 + j;
        bf0[j] = (__bf16)W1[k * 32 + l15];
        bf1[j] = (__bf16)W1[k * 32 + 16 + l15];
      }
      acc0 = __builtin_amdgcn_mfma_f32_16x16x32_bf16(a, bf0, acc0, 0, 0, 0);
      acc1 = __builtin_amdgcn_mfma_f32_16x16x32_bf16(a, bf1, acc1, 0, 0, 0);
    }
  }

  // ---- bias + ELU; per-wave h-transpose through a private 4KB slice of
  // xb[0] (safe: xb[0] last read in consume(18), barrier'ed at end of c=18;
  // each wave touches only its own slice -> wave-local lgkmcnt suffices).
  unsigned short* hl = ((unsigned short*)&xb[0][0][0]) + wave * 2048;
#pragma unroll
  for (int r = 0; r < 4; ++r) {
    int hrow = lh * 4 + r;  // C/D layout: row=(lane>>4)*4+reg, col=lane&15
    float h0 = acc0[r] + bias0;
    float h1 = acc1[r] + bias1;
    h0 = h0 > 0.f ? h0 : (__expf(h0) - 1.f);
    h1 = h1 > 0.f ? h1 : (__expf(h1) - 1.f);
    __bf16 v0 = (__bf16)h0, v1 = (__bf16)h1;
    hl[hrow * 40 + l15] = __builtin_bit_cast(unsigned short, v0);
    hl[hrow * 40 + 16 + l15] = __builtin_bit_cast(unsigned short, v1);
  }
  asm volatile("s_waitcnt lgkmcnt(0)" ::: "memory");
  __builtin_amdgcn_sched_barrier(0);
  bf16x8 ha =
      __builtin_bit_cast(bf16x8, *(const u16x8*)(hl + l15 * 40 + lh * 8));

  // ---- GEMM2: out tiles over 8 ntiles of 16 cols ----
  f32x4 o[8];
#pragma unroll
  for (int nt = 0; nt < 8; ++nt) {
    bf16x8 bw;
    if (USE_WS) {
      bw = __builtin_bit_cast(bf16x8,
                              *(const u16x8*)(wsB2 + nt * 512 + lane * 8));
    } else {
#pragma unroll
      for (int j = 0; j < 8; ++j)
        bw[j] = (__bf16)W2[(lh * 8 + j) * 128 + nt * 16 + l15];
    }
    f32x4 z = {0.f, 0.f, 0.f, 0.f};
    o[nt] = __builtin_amdgcn_mfma_f32_16x16x32_bf16(ha, bw, z, 0, 0, 0);
  }

  const long ebase = e0 + wave * 16;
#pragma unroll
  for (int nt = 0; nt < 8; ++nt) {
    float bb = b2[nt * 16 + l15];
#pragma unroll
    for (int r = 0; r < 4; ++r) {
      long e = ebase + lh * 4 + r;
      if (e < nE) out[e * 128 + nt * 16 + l15] = o[nt][r] + bb;
    }
  }
}

extern "C" void kernel_launch(void* const* d_in, const int* in_sizes, int n_in,
                              void* d_out, int out_size, void* d_ws,
                              size_t ws_size, hipStream_t stream) {
  const float* src = (const float*)d_in[0];
  const float* dst = (const float*)d_in[1];
  const float* ea = (const float*)d_in[2];
  // d_in[3] = u (unused), d_in[4] = batch (unused)
  const float* W1 = (const float*)d_in[5];
  const float* b1 = (const float*)d_in[6];
  const float* W2 = (const float*)d_in[7];
  const float* b2 = (const float*)d_in[8];
  float* out = (float*)d_out;

  const int nE = in_sizes[0] / 512;  // 200000

  unsigned short* wsB1 = (unsigned short*)d_ws;
  unsigned short* wsB2 = wsB1 + 40960;
  const bool use_ws =
      ws_size >= 45056 * sizeof(unsigned short) && (nE & 63) == 0;

  if (use_ws) {
    const int nblocks = nE / 64;  // 3125
    prep_w_kernel<<<176, 256, 0, stream>>>(W1, W2, wsB1, wsB2);
    edge_mlp_kernel<true><<<nblocks, 256, 0, stream>>>(
        src, dst, ea, W1, b1, W2, b2, wsB1, wsB2, out, nE);
  } else {
    const long strips = (nE + 15) / 16;
    const int nblocks = (int)((strips + 3) / 4);
    edge_mlp_kernel<false><<<nblocks, 256, 0, stream>>>(
        src, dst, ea, W1, b1, W2, b2, nullptr, nullptr, out, nE);
  }
}